// Round 5
// baseline (893.606 us; speedup 1.0000x reference)
//
#include <hip/hip_runtime.h>
#include <math.h>

#define N_IMG 32
#define N_ATOM 400000
#define NE (N_ATOM*3)        // 1,200,000 floats per image row
#define NE4 (NE/4)           // 300,000 float4 per image row
#define KMAXC 0.1f
#define DLTKC 0.02f
#define EPSE 0.1f

// ws layout (floats):
#define OFF_CO  160  // coeffs A[30],B[30],C[30] at ws[160..249]
#define OFF_CTR 250  // launch counter (uint) — memset to 0 each launch
#define OFF_PART 256 // per-slot partials: NSUM rows x NBXPP floats (transposed)
#define NSUM 151
#define OFF_SDD 0    // 31 per-link |d|^2
#define OFF_SPM 31   // 30 d[j-1].d[j]
#define OFF_SFP 61   // 30 f[j].d[j-1]
#define OFF_SFM 91   // 30 f[j].d[j]
#define OFF_SFF 121  // 30 |f[j]|^2
#define NBXPP 592    // padded row length for transposed partials

#define NBXP 586     // pass1 column-blocks (2 float4 cols per thread)
#define NBX2 1172    // pass2 column-blocks (1 float4 col per thread)
#define NCHUNK 5     // 5 chunks x 6 interior images = images 1..30
#define TOTB (NBXP * NCHUNK)   // 2930 blocks in K1

__device__ __forceinline__ float dot4(float4 a, float4 b) {
    return a.x*b.x + a.y*b.y + a.z*b.z + a.w*b.w;
}
__device__ __forceinline__ float4 sub4(float4 a, float4 b) {
    return make_float4(a.x-b.x, a.y-b.y, a.z-b.z, a.w-b.w);
}

// Full-wave (64-lane) sum via DPP on the VALU pipe. Lane 63 has the total.
__device__ __forceinline__ float wred_dpp(float x) {
    x += __int_as_float(__builtin_amdgcn_update_dpp(0, __float_as_int(x), 0x111, 0xf, 0xf, false)); // row_shr:1
    x += __int_as_float(__builtin_amdgcn_update_dpp(0, __float_as_int(x), 0x112, 0xf, 0xf, false)); // row_shr:2
    x += __int_as_float(__builtin_amdgcn_update_dpp(0, __float_as_int(x), 0x114, 0xf, 0xf, false)); // row_shr:4
    x += __int_as_float(__builtin_amdgcn_update_dpp(0, __float_as_int(x), 0x118, 0xf, 0xf, false)); // row_shr:8
    x += __int_as_float(__builtin_amdgcn_update_dpp(0, __float_as_int(x), 0x142, 0xa, 0xf, false)); // row_bcast:15
    x += __int_as_float(__builtin_amdgcn_update_dpp(0, __float_as_int(x), 0x143, 0xc, 0xf, false)); // row_bcast:31
    return x;
}

// K1: pass1 + last-block {reduce + coeff}. Grid (NBXP, NCHUNK), inner loop
// byte-identical to R2's eb_pass1 (113us). Tail: rocPRIM-style last-block
// fall-through. R4 POST-MORTEM: the counter MUST start at 0 — the harness
// re-poisons ws between runs, and a garbage base makes the "mod TOTB"
// election fire on a mid-order block that reads unpublished partials (the
// R4 correctness failure). kernel_launch now hipMemsetAsync's it to 0, and
// the election is the exact old==TOTB-1.
__global__ __launch_bounds__(256) void eb_pass1r(const float* __restrict__ pos,
                                                 const float* __restrict__ frc,
                                                 const float* __restrict__ eng,
                                                 float* __restrict__ part,
                                                 float* __restrict__ co,
                                                 unsigned int* __restrict__ counter) {
    const int c = blockIdx.y;
    const int j0 = 1 + 6 * c;
    const float4* pos4 = reinterpret_cast<const float4*>(pos);
    const float4* frc4 = reinterpret_cast<const float4*>(frc);

    float sdd[7], spm[6], sfp[6], sfm[6], sff[6];
#pragma unroll
    for (int i = 0; i < 7; ++i) sdd[i] = 0.f;
#pragma unroll
    for (int i = 0; i < 6; ++i) { spm[i] = 0.f; sfp[i] = 0.f; sfm[i] = 0.f; sff[i] = 0.f; }

    for (int t = blockIdx.x * 256 + threadIdx.x; t < NE4; t += 256 * NBXP) {
        float4 p[8], f[6];
#pragma unroll
        for (int i = 0; i < 8; ++i) p[i] = pos4[(size_t)(j0 - 1 + i) * NE4 + t];
#pragma unroll
        for (int i = 0; i < 6; ++i) f[i] = frc4[(size_t)(j0 + i) * NE4 + t];
        float4 d[7];
#pragma unroll
        for (int i = 0; i < 7; ++i) d[i] = sub4(p[i + 1], p[i]);   // d[i] = link (j0-1+i)
#pragma unroll
        for (int i = 0; i < 7; ++i) sdd[i] += dot4(d[i], d[i]);
#pragma unroll
        for (int jj = 0; jj < 6; ++jj) {
            spm[jj] += dot4(d[jj], d[jj + 1]);   // d[j-1].d[j]
            sfp[jj] += dot4(f[jj], d[jj]);       // f.d[j-1]
            sfm[jj] += dot4(f[jj], d[jj + 1]);   // f.d[j]
            sff[jj] += dot4(f[jj], f[jj]);
        }
    }

    float v[31];
#pragma unroll
    for (int i = 0; i < 7; ++i) v[i] = sdd[i];
#pragma unroll
    for (int i = 0; i < 6; ++i) { v[7 + i] = spm[i]; v[13 + i] = sfp[i]; v[19 + i] = sfm[i]; v[25 + i] = sff[i]; }

    __shared__ float red[4][31];
    {
        const int wave = threadIdx.x >> 6;
        const int lane = threadIdx.x & 63;
#pragma unroll
        for (int s = 0; s < 31; ++s) {
            float r = wred_dpp(v[s]);
            if (lane == 63) red[wave][s] = r;
        }
    }
    __syncthreads();
    {
        const int s = threadIdx.x;
        if (s < 31) {
            float r = red[0][s] + red[1][s] + red[2][s] + red[3][s];
            int slot; bool owned = true;
            if (s < 7)       { owned = (s < 6) || (c == NCHUNK - 1); slot = OFF_SDD + (j0 - 1) + s; }
            else if (s < 13) slot = OFF_SPM + (j0 - 1) + (s - 7);
            else if (s < 19) slot = OFF_SFP + (j0 - 1) + (s - 13);
            else if (s < 25) slot = OFF_SFM + (j0 - 1) + (s - 19);
            else             slot = OFF_SFF + (j0 - 1) + (s - 25);
            if (owned) part[(size_t)slot * NBXPP + blockIdx.x] = r;   // slot-major
        }
    }

    // ---- publish partials, elect the true last block ----
    __threadfence();          // device-scope release: partials visible chip-wide
    __syncthreads();
    __shared__ int lastFlag;
    if (threadIdx.x == 0) {
        unsigned int old = atomicAdd(counter, 1u);
        lastFlag = (old == (unsigned)(TOTB - 1)) ? 1 : 0;   // counter memset to 0
    }
    __syncthreads();
    if (!lastFlag) return;
    __threadfence();          // device-scope acquire: invalidate stale caches

    // ---- last block: reduce partials (wave w owns slots w, w+4, ...) ----
    __shared__ float ssum[NSUM];
    {
        const int wave = threadIdx.x >> 6;
        const int lane = threadIdx.x & 63;
        for (int s = wave; s < NSUM; s += 4) {
            float acc = 0.f;
            for (int r = lane; r < NBXP; r += 64)
                acc += part[(size_t)s * NBXPP + r];
            float t = wred_dpp(acc);
            if (lane == 63) ssum[s] = t;
        }
    }
    __syncthreads();

    // ---- coeff (threads 0..29) ----
    if (threadIdx.x < N_IMG - 2) {
        const int jj = threadIdx.x;
        float e[N_IMG];
        float emin = 1e30f, emax = -1e30f;
        int imax = 0;
        for (int i = 0; i < N_IMG; ++i) {
            float vv = eng[i];
            e[i] = vv;
            if (vv < emin) emin = vv;
            if (vv > emax) { emax = vv; imax = i; }   // strict > -> argmax
        }
        const float eref = emin - EPSE;
        float e0 = e[jj], e1 = e[jj + 1], e2 = e[jj + 2];
        float eim = fmaxf(e1, e0);
        float km = KMAXC - DLTKC * (emax - eim) / (emax - eref);
        if (eim < eref) km = KMAXC - DLTKC;
        float eip = fmaxf(e2, e1);
        float kp = KMAXC - DLTKC * (emax - eip) / (emax - eref);
        if (eip < eref) kp = KMAXC - DLTKC;

        float pp = (e2 > e1 && e1 > e0) ? 1.f : 0.f;
        float mm = (e2 < e1 && e1 < e0) ? 1.f : 0.f;
        float nb = 1.f - fmaxf(pp, mm);
        float mp = ((e2 > e1) ? 1.f : 0.f) * nb;
        float mq = ((e2 < e1) ? 1.f : 0.f) * nb;
        float dvmax = fmaxf(fabsf(e2 - e1), fabsf(e0 - e1));
        float dvmin = fminf(fabsf(e2 - e1), fabsf(e0 - e1));
        float a = pp + dvmax * mp + dvmin * mq;   // coeff of tau_p
        float bb = mm + dvmin * mp + dvmax * mq;  // coeff of tau_m
        float Spp = ssum[OFF_SDD + jj];
        float Smm = ssum[OFF_SDD + jj + 1];
        float Spm = ssum[OFF_SPM + jj];
        float Sfp = ssum[OFF_SFP + jj];
        float Sfm = ssum[OFF_SFM + jj];
        float Sff = ssum[OFF_SFF + jj];
        float ntau2 = a * a * Spp + 2.f * a * bb * Spm + bb * bb * Smm;
        float ntau = sqrtf(ntau2);
        float ta = a / ntau, tb = bb / ntau;
        float fpar = ta * Sfp + tb * Sfm;                       // dot(frc, tau)
        float spar = kp * sqrtf(Smm) - km * sqrtf(Spp);         // spr_para magnitude
        float ffpp = Sff - fpar * fpar;                         // |frc_perp|^2
        float strau = ta * (kp * Spm - km * Spp) + tb * (kp * Smm - km * Spm); // dot(spr,tau)
        float Sss = kp * kp * Smm - 2.f * kp * km * Spm + km * km * Spp;       // dot(spr,spr)
        float sspp = Sss - 2.f * spar * strau + spar * spar;    // |spr_perp|^2
        float Ssf = kp * Sfm - km * Sfp;                        // dot(spr,frc)
        float spfp = Ssf - fpar * strau;                        // dot(spr_perp,frc_perp)
        float sw = (2.0f / 3.14159265358979323846f) * atan2f(ffpp, sspp);
        float cc = spfp * sw;
        float g = (jj == imax) ? 2.f : 1.f;                     // .at[i_raw].multiply(2.0)
        float w = (cc - g) * fpar / ntau;
        co[jj]      = 1.f - cc;       // A: coeff of frc
        co[30 + jj] = kp + w * bb;    // B: coeff of tau_m (=d[j])
        co[60 + jj] = w * a - km;     // C: coeff of tau_p (=d[j-1])
    }
}

// K2: pass2, identical to R1/R2. Grid (NBX2, NCHUNK).
__global__ __launch_bounds__(256) void eb_pass2(const float* __restrict__ pos,
                                                const float* __restrict__ frc,
                                                const float* __restrict__ co,
                                                float* __restrict__ out) {
    __shared__ float A[30], B[30], C[30];
    if (threadIdx.x < 30) {
        A[threadIdx.x] = co[threadIdx.x];
        B[threadIdx.x] = co[30 + threadIdx.x];
        C[threadIdx.x] = co[60 + threadIdx.x];
    }
    __syncthreads();
    const int t = blockIdx.x * 256 + threadIdx.x;
    if (t >= NE4) return;
    const int c = blockIdx.y;
    const int j0 = 1 + 6 * c;
    const float4* pos4 = reinterpret_cast<const float4*>(pos);
    const float4* frc4 = reinterpret_cast<const float4*>(frc);
    float4* out4 = reinterpret_cast<float4*>(out);

    float4 p[8], f[6];
#pragma unroll
    for (int i = 0; i < 8; ++i) p[i] = pos4[(size_t)(j0 - 1 + i) * NE4 + t];
#pragma unroll
    for (int i = 0; i < 6; ++i) f[i] = frc4[(size_t)(j0 + i) * NE4 + t];

    if (c == 0) out4[t] = frc4[t];                                       // out[0]=frc[0]
    if (c == NCHUNK - 1) {
        size_t i31 = (size_t)31 * NE4 + t;
        out4[i31] = frc4[i31];                                           // out[31]=frc[31]
    }

    float4 d[7];
#pragma unroll
    for (int i = 0; i < 7; ++i) d[i] = sub4(p[i + 1], p[i]);   // d[i] = link (j0-1+i)
#pragma unroll
    for (int jj = 0; jj < 6; ++jj) {
        const int j = j0 + jj;
        const int g = j - 1;
        float ca = A[g], cb = B[g], cd = C[g];
        float4 o;
        o.x = ca * f[jj].x + cb * d[jj + 1].x + cd * d[jj].x;
        o.y = ca * f[jj].y + cb * d[jj + 1].y + cd * d[jj].y;
        o.z = ca * f[jj].z + cb * d[jj + 1].z + cd * d[jj].z;
        o.w = ca * f[jj].w + cb * d[jj + 1].w + cd * d[jj].w;
        out4[(size_t)j * NE4 + t] = o;
    }
}

extern "C" void kernel_launch(void* const* d_in, const int* in_sizes, int n_in,
                              void* d_out, int out_size, void* d_ws, size_t ws_size,
                              hipStream_t stream) {
    const float* pos = (const float*)d_in[0];
    const float* frc = (const float*)d_in[1];
    const float* eng = (const float*)d_in[2];
    float* out = (float*)d_out;
    float* ws = (float*)d_ws;
    float* co   = ws + OFF_CO;                                   // [160..249]
    unsigned int* counter = (unsigned int*)(ws + OFF_CTR);
    float* part = ws + OFF_PART;                                 // NSUM x NBXPP

    // R4 fix: counter MUST start at 0 (ws is re-poisoned between runs).
    hipMemsetAsync(counter, 0, sizeof(unsigned int), stream);

    eb_pass1r<<<dim3(NBXP, NCHUNK), 256, 0, stream>>>(pos, frc, eng, part, co, counter);
    eb_pass2<<<dim3(NBX2, NCHUNK), 256, 0, stream>>>(pos, frc, co, out);
}

// Round 6
// 503.910 us; speedup vs baseline: 1.7733x; 1.7733x over previous
//
#include <hip/hip_runtime.h>
#include <math.h>

#define N_IMG 32
#define N_ATOM 400000
#define NE (N_ATOM*3)        // 1,200,000 floats per image row
#define NE4 (NE/4)           // 300,000 float4 per image row
#define KMAXC 0.1f
#define DLTKC 0.02f
#define EPSE 0.1f

// ws layout (floats):
#define OFF_PART 256 // per-slot partials: NSUM rows x NBXPP floats (transposed)
#define NSUM 151
#define OFF_SDD 0    // 31 per-link |d|^2
#define OFF_SPM 31   // 30 d[j-1].d[j]
#define OFF_SFP 61   // 30 f[j].d[j-1]
#define OFF_SFM 91   // 30 f[j].d[j]
#define OFF_SFF 121  // 30 |f[j]|^2
#define NBXPP 592    // padded row length for transposed partials

#define NBXP 586     // pass1 column-blocks (2 float4 cols per thread)
#define NBX2 1172    // pass2 column-blocks (1 float4 col per thread)
#define NCHUNK 5     // 5 chunks x 6 interior images = images 1..30

__device__ __forceinline__ float dot4(float4 a, float4 b) {
    return a.x*b.x + a.y*b.y + a.z*b.z + a.w*b.w;
}
__device__ __forceinline__ float4 sub4(float4 a, float4 b) {
    return make_float4(a.x-b.x, a.y-b.y, a.z-b.z, a.w-b.w);
}

// Full-wave (64-lane) sum via DPP on the VALU pipe. Lane 63 has the total.
__device__ __forceinline__ float wred_dpp(float x) {
    x += __int_as_float(__builtin_amdgcn_update_dpp(0, __float_as_int(x), 0x111, 0xf, 0xf, false)); // row_shr:1
    x += __int_as_float(__builtin_amdgcn_update_dpp(0, __float_as_int(x), 0x112, 0xf, 0xf, false)); // row_shr:2
    x += __int_as_float(__builtin_amdgcn_update_dpp(0, __float_as_int(x), 0x114, 0xf, 0xf, false)); // row_shr:4
    x += __int_as_float(__builtin_amdgcn_update_dpp(0, __float_as_int(x), 0x118, 0xf, 0xf, false)); // row_shr:8
    x += __int_as_float(__builtin_amdgcn_update_dpp(0, __float_as_int(x), 0x142, 0xa, 0xf, false)); // row_bcast:15
    x += __int_as_float(__builtin_amdgcn_update_dpp(0, __float_as_int(x), 0x143, 0xc, 0xf, false)); // row_bcast:31
    return x;
}

// K1: R2's proven pass1 (113us), verbatim. Writes transposed non-atomic
// partials — every slot written unconditionally each run (poison-safe, no
// init dispatch). NO fences/atomics: R5 showed per-block __threadfence()
// on this 8-XCD chip nukes per-XCD L2s and slows the main loop 5.4x; the
// kernel boundary does the same release once, in hardware, for free.
__global__ __launch_bounds__(256) void eb_pass1(const float* __restrict__ pos,
                                                const float* __restrict__ frc,
                                                float* __restrict__ part) {
    const int c = blockIdx.y;
    const int j0 = 1 + 6 * c;
    const float4* pos4 = reinterpret_cast<const float4*>(pos);
    const float4* frc4 = reinterpret_cast<const float4*>(frc);

    float sdd[7], spm[6], sfp[6], sfm[6], sff[6];
#pragma unroll
    for (int i = 0; i < 7; ++i) sdd[i] = 0.f;
#pragma unroll
    for (int i = 0; i < 6; ++i) { spm[i] = 0.f; sfp[i] = 0.f; sfm[i] = 0.f; sff[i] = 0.f; }

    for (int t = blockIdx.x * 256 + threadIdx.x; t < NE4; t += 256 * NBXP) {
        float4 p[8], f[6];
#pragma unroll
        for (int i = 0; i < 8; ++i) p[i] = pos4[(size_t)(j0 - 1 + i) * NE4 + t];
#pragma unroll
        for (int i = 0; i < 6; ++i) f[i] = frc4[(size_t)(j0 + i) * NE4 + t];
        float4 d[7];
#pragma unroll
        for (int i = 0; i < 7; ++i) d[i] = sub4(p[i + 1], p[i]);   // d[i] = link (j0-1+i)
#pragma unroll
        for (int i = 0; i < 7; ++i) sdd[i] += dot4(d[i], d[i]);
#pragma unroll
        for (int jj = 0; jj < 6; ++jj) {
            spm[jj] += dot4(d[jj], d[jj + 1]);   // d[j-1].d[j]
            sfp[jj] += dot4(f[jj], d[jj]);       // f.d[j-1]
            sfm[jj] += dot4(f[jj], d[jj + 1]);   // f.d[j]
            sff[jj] += dot4(f[jj], f[jj]);
        }
    }

    float v[31];
#pragma unroll
    for (int i = 0; i < 7; ++i) v[i] = sdd[i];
#pragma unroll
    for (int i = 0; i < 6; ++i) { v[7 + i] = spm[i]; v[13 + i] = sfp[i]; v[19 + i] = sfm[i]; v[25 + i] = sff[i]; }

    __shared__ float red[4][31];
    {
        const int wave = threadIdx.x >> 6;
        const int lane = threadIdx.x & 63;
#pragma unroll
        for (int s = 0; s < 31; ++s) {
            float r = wred_dpp(v[s]);
            if (lane == 63) red[wave][s] = r;
        }
    }
    __syncthreads();
    const int s = threadIdx.x;
    if (s < 31) {
        float r = red[0][s] + red[1][s] + red[2][s] + red[3][s];
        int slot; bool owned = true;
        if (s < 7)       { owned = (s < 6) || (c == NCHUNK - 1); slot = OFF_SDD + (j0 - 1) + s; }
        else if (s < 13) slot = OFF_SPM + (j0 - 1) + (s - 7);
        else if (s < 19) slot = OFF_SFP + (j0 - 1) + (s - 13);
        else if (s < 25) slot = OFF_SFM + (j0 - 1) + (s - 19);
        else             slot = OFF_SFF + (j0 - 1) + (s - 25);
        if (owned) part[(size_t)slot * NBXPP + blockIdx.x] = r;   // slot-major
    }
}

// K2: per-block {reduce own chunk's 31 slots + coeff for 6 images} + pass2.
// The 31x586-float prologue (73 KB, read-only, L2-resident) replaces the
// eb_reduce and eb_coeff DISPATCHES — redundancy is ~427 MB of L2 reads
// aggregate (~12us chip-wide), vs ~90us of dispatch overhead saved.
__global__ __launch_bounds__(256) void eb_pass2r(const float* __restrict__ pos,
                                                 const float* __restrict__ frc,
                                                 const float* __restrict__ eng,
                                                 const float* __restrict__ part,
                                                 float* __restrict__ out) {
    const int c = blockIdx.y;
    const int j0 = 1 + 6 * c;
    const int base = j0 - 1;           // = 6c: first coeff index of this chunk

    // ---- prologue: reduce the 31 partial-rows this chunk needs ----
    // local slot s: 0..6 -> SDD[base+s]; 7..12 -> SPM[base+s-7];
    // 13..18 -> SFP; 19..24 -> SFM; 25..30 -> SFF.
    __shared__ float ssum[31];
    {
        const int wave = threadIdx.x >> 6;     // 4 waves
        const int lane = threadIdx.x & 63;
        for (int s = wave; s < 31; s += 4) {
            int row;
            if (s < 7)       row = OFF_SDD + base + s;
            else if (s < 13) row = OFF_SPM + base + (s - 7);
            else if (s < 19) row = OFF_SFP + base + (s - 13);
            else if (s < 25) row = OFF_SFM + base + (s - 19);
            else             row = OFF_SFF + base + (s - 25);
            float acc = 0.f;
            for (int r = lane; r < NBXP; r += 64)
                acc += part[(size_t)row * NBXPP + r];
            float tt = wred_dpp(acc);
            if (lane == 63) ssum[s] = tt;
        }
    }
    __syncthreads();

    // ---- coeff for this chunk's 6 images (threads 0..5) ----
    __shared__ float As[6], Bs[6], Cs[6];
    if (threadIdx.x < 6) {
        const int jl = threadIdx.x;        // local image index in chunk
        const int jj = base + jl;          // global coeff index 0..29
        float e[N_IMG];
        float emin = 1e30f, emax = -1e30f;
        int imax = 0;
        for (int i = 0; i < N_IMG; ++i) {
            float vv = eng[i];
            e[i] = vv;
            if (vv < emin) emin = vv;
            if (vv > emax) { emax = vv; imax = i; }   // strict > -> argmax
        }
        const float eref = emin - EPSE;
        float e0 = e[jj], e1 = e[jj + 1], e2 = e[jj + 2];
        float eim = fmaxf(e1, e0);
        float km = KMAXC - DLTKC * (emax - eim) / (emax - eref);
        if (eim < eref) km = KMAXC - DLTKC;
        float eip = fmaxf(e2, e1);
        float kp = KMAXC - DLTKC * (emax - eip) / (emax - eref);
        if (eip < eref) kp = KMAXC - DLTKC;

        float pp = (e2 > e1 && e1 > e0) ? 1.f : 0.f;
        float mm = (e2 < e1 && e1 < e0) ? 1.f : 0.f;
        float nb = 1.f - fmaxf(pp, mm);
        float mp = ((e2 > e1) ? 1.f : 0.f) * nb;
        float mq = ((e2 < e1) ? 1.f : 0.f) * nb;
        float dvmax = fmaxf(fabsf(e2 - e1), fabsf(e0 - e1));
        float dvmin = fminf(fabsf(e2 - e1), fabsf(e0 - e1));
        float a = pp + dvmax * mp + dvmin * mq;   // coeff of tau_p
        float bb = mm + dvmin * mp + dvmax * mq;  // coeff of tau_m
        float Spp = ssum[jl];          // SDD[base+jl]
        float Smm = ssum[jl + 1];      // SDD[base+jl+1]
        float Spm = ssum[7 + jl];
        float Sfp = ssum[13 + jl];
        float Sfm = ssum[19 + jl];
        float Sff = ssum[25 + jl];
        float ntau2 = a * a * Spp + 2.f * a * bb * Spm + bb * bb * Smm;
        float ntau = sqrtf(ntau2);
        float ta = a / ntau, tb = bb / ntau;
        float fpar = ta * Sfp + tb * Sfm;                       // dot(frc, tau)
        float spar = kp * sqrtf(Smm) - km * sqrtf(Spp);         // spr_para magnitude
        float ffpp = Sff - fpar * fpar;                         // |frc_perp|^2
        float strau = ta * (kp * Spm - km * Spp) + tb * (kp * Smm - km * Spm); // dot(spr,tau)
        float Sss = kp * kp * Smm - 2.f * kp * km * Spm + km * km * Spp;       // dot(spr,spr)
        float sspp = Sss - 2.f * spar * strau + spar * spar;    // |spr_perp|^2
        float Ssf = kp * Sfm - km * Sfp;                        // dot(spr,frc)
        float spfp = Ssf - fpar * strau;                        // dot(spr_perp,frc_perp)
        float sw = (2.0f / 3.14159265358979323846f) * atan2f(ffpp, sspp);
        float cc = spfp * sw;
        float g = (jj == imax) ? 2.f : 1.f;                     // .at[i_raw].multiply(2.0)
        float w = (cc - g) * fpar / ntau;
        As[jl] = 1.f - cc;       // A: coeff of frc
        Bs[jl] = kp + w * bb;    // B: coeff of tau_m (=d[j])
        Cs[jl] = w * a - km;     // C: coeff of tau_p (=d[j-1])
    }
    __syncthreads();

    // ---- main body: identical to R2's eb_pass2 ----
    const int t = blockIdx.x * 256 + threadIdx.x;
    if (t >= NE4) return;
    const float4* pos4 = reinterpret_cast<const float4*>(pos);
    const float4* frc4 = reinterpret_cast<const float4*>(frc);
    float4* out4 = reinterpret_cast<float4*>(out);

    float4 p[8], f[6];
#pragma unroll
    for (int i = 0; i < 8; ++i) p[i] = pos4[(size_t)(j0 - 1 + i) * NE4 + t];
#pragma unroll
    for (int i = 0; i < 6; ++i) f[i] = frc4[(size_t)(j0 + i) * NE4 + t];

    if (c == 0) out4[t] = frc4[t];                                       // out[0]=frc[0]
    if (c == NCHUNK - 1) {
        size_t i31 = (size_t)31 * NE4 + t;
        out4[i31] = frc4[i31];                                           // out[31]=frc[31]
    }

    float4 d[7];
#pragma unroll
    for (int i = 0; i < 7; ++i) d[i] = sub4(p[i + 1], p[i]);   // d[i] = link (j0-1+i)
#pragma unroll
    for (int jj = 0; jj < 6; ++jj) {
        float ca = As[jj], cb = Bs[jj], cd = Cs[jj];
        float4 o;
        o.x = ca * f[jj].x + cb * d[jj + 1].x + cd * d[jj].x;
        o.y = ca * f[jj].y + cb * d[jj + 1].y + cd * d[jj].y;
        o.z = ca * f[jj].z + cb * d[jj + 1].z + cd * d[jj].z;
        o.w = ca * f[jj].w + cb * d[jj + 1].w + cd * d[jj].w;
        out4[(size_t)(j0 + jj) * NE4 + t] = o;
    }
}

extern "C" void kernel_launch(void* const* d_in, const int* in_sizes, int n_in,
                              void* d_out, int out_size, void* d_ws, size_t ws_size,
                              hipStream_t stream) {
    const float* pos = (const float*)d_in[0];
    const float* frc = (const float*)d_in[1];
    const float* eng = (const float*)d_in[2];
    float* out = (float*)d_out;
    float* ws = (float*)d_ws;
    float* part = ws + OFF_PART;      // NSUM x NBXPP (transposed)

    eb_pass1<<<dim3(NBXP, NCHUNK), 256, 0, stream>>>(pos, frc, part);
    eb_pass2r<<<dim3(NBX2, NCHUNK), 256, 0, stream>>>(pos, frc, eng, part, out);
}

// Round 7
// 429.012 us; speedup vs baseline: 2.0829x; 1.1746x over previous
//
#include <hip/hip_runtime.h>
#include <math.h>

#define N_IMG 32
#define N_ATOM 400000
#define NE (N_ATOM*3)        // 1,200,000 floats per image row
#define NE4 (NE/4)           // 300,000 float4 per image row
#define KMAXC 0.1f
#define DLTKC 0.02f
#define EPSE 0.1f

// ws layout (floats): partials at OFF_PART, NSUM rows x PADW (slot-major).
// Global slot numbering (unchanged): SDD[0..30] = rows 0..30, SPM[g]=31+g,
// SFP[g]=61+g, SFM[g]=91+g, SFF[g]=121+g for coeff index g=0..29.
#define OFF_PART 256
#define NSUM 151
#define PADW 592     // row width = NBX1 padded

#define NBX1 586     // pass1 column-blocks (2 float4 cols per thread)
#define NBX2 1172    // pass2 column-blocks (1 float4 col per thread)
#define NCH3 10      // 10 chunks x 3 interior images = images 1..30

__device__ __forceinline__ float dot4(float4 a, float4 b) {
    return a.x*b.x + a.y*b.y + a.z*b.z + a.w*b.w;
}
__device__ __forceinline__ float4 sub4(float4 a, float4 b) {
    return make_float4(a.x-b.x, a.y-b.y, a.z-b.z, a.w-b.w);
}

// Full-wave (64-lane) sum via DPP on the VALU pipe. Lane 63 has the total.
__device__ __forceinline__ float wred_dpp(float x) {
    x += __int_as_float(__builtin_amdgcn_update_dpp(0, __float_as_int(x), 0x111, 0xf, 0xf, false)); // row_shr:1
    x += __int_as_float(__builtin_amdgcn_update_dpp(0, __float_as_int(x), 0x112, 0xf, 0xf, false)); // row_shr:2
    x += __int_as_float(__builtin_amdgcn_update_dpp(0, __float_as_int(x), 0x114, 0xf, 0xf, false)); // row_shr:4
    x += __int_as_float(__builtin_amdgcn_update_dpp(0, __float_as_int(x), 0x118, 0xf, 0xf, false)); // row_shr:8
    x += __int_as_float(__builtin_amdgcn_update_dpp(0, __float_as_int(x), 0x142, 0xa, 0xf, false)); // row_bcast:15
    x += __int_as_float(__builtin_amdgcn_update_dpp(0, __float_as_int(x), 0x143, 0xc, 0xf, false)); // row_bcast:31
    return x;
}

// K1: 3-image chunks. Grid (NBX1, NCH3). Chunk c: images j0..j0+2, j0=1+3c;
// loads pos[j0-1..j0+3] (5) + frc[j0..j0+2] (3) = 8 streams/iter — fits the
// compiler's 64-VGPR allocation WITH all loads in flight (R0/R1's 14-stream
// version serialized into vmcnt groups; that was the 113us latency cap).
// Owns SDD links 3c..3c+2 (+30 for c==9) and SPM/SFP/SFM/SFF for g=3c..3c+2.
// Partials non-atomic, every slot rewritten each run (poison-safe).
__global__ __launch_bounds__(256) void eb_pass1(const float* __restrict__ pos,
                                                const float* __restrict__ frc,
                                                float* __restrict__ part) {
    const int c = blockIdx.y;
    const int j0 = 1 + 3 * c;
    const float4* pos4 = reinterpret_cast<const float4*>(pos);
    const float4* frc4 = reinterpret_cast<const float4*>(frc);

    float s16[16];
#pragma unroll
    for (int i = 0; i < 16; ++i) s16[i] = 0.f;

    for (int t = blockIdx.x * 256 + threadIdx.x; t < NE4; t += 256 * NBX1) {
        float4 p[5], f[3];
#pragma unroll
        for (int i = 0; i < 5; ++i) p[i] = pos4[(size_t)(j0 - 1 + i) * NE4 + t];
#pragma unroll
        for (int i = 0; i < 3; ++i) f[i] = frc4[(size_t)(j0 + i) * NE4 + t];
        float4 d[4];
#pragma unroll
        for (int i = 0; i < 4; ++i) d[i] = sub4(p[i + 1], p[i]);   // link 3c+i
#pragma unroll
        for (int i = 0; i < 4; ++i) s16[i] += dot4(d[i], d[i]);
#pragma unroll
        for (int i = 0; i < 3; ++i) {
            s16[4 + i]  += dot4(d[i], d[i + 1]);   // SPM[3c+i]
            s16[7 + i]  += dot4(f[i], d[i]);       // SFP
            s16[10 + i] += dot4(f[i], d[i + 1]);   // SFM
            s16[13 + i] += dot4(f[i], f[i]);       // SFF
        }
    }

    __shared__ float red[4][16];
    {
        const int wave = threadIdx.x >> 6;
        const int lane = threadIdx.x & 63;
#pragma unroll
        for (int s = 0; s < 16; ++s) {
            float r = wred_dpp(s16[s]);
            if (lane == 63) red[wave][s] = r;
        }
    }
    __syncthreads();
    const int s = threadIdx.x;
    if (s < 16) {
        float r = red[0][s] + red[1][s] + red[2][s] + red[3][s];
        int slot; bool owned = true;
        if (s < 4)       { owned = (s < 3) || (c == NCH3 - 1); slot = 3 * c + s; }
        else if (s < 7)  slot = 31 + 3 * c + (s - 4);
        else if (s < 10) slot = 61 + 3 * c + (s - 7);
        else if (s < 13) slot = 91 + 3 * c + (s - 10);
        else             slot = 121 + 3 * c + (s - 13);
        if (owned) part[(size_t)slot * PADW + blockIdx.x] = r;   // slot-major
    }
}

// K2: 3-image chunks. Grid (NBX2, NCH3). Prologue reduces the 16 partial
// rows this chunk needs with a 4-deep INTERLEAVED accumulator (R6's serial
// r-loop was a dependent load chain ~15us/block — the 178us regression).
// Coeff section: no e[32] scratch array (dynamic-index -> local memory);
// emin/emax/imax via scalar loop + 3 direct eng loads. Main body: 8 loads
// + 3 stores per thread.
__global__ __launch_bounds__(256) void eb_pass2r(const float* __restrict__ pos,
                                                 const float* __restrict__ frc,
                                                 const float* __restrict__ eng,
                                                 const float* __restrict__ part,
                                                 float* __restrict__ out) {
    const int c = blockIdx.y;
    const int j0 = 1 + 3 * c;
    const int base = 3 * c;            // coeff index base (g = j-1)

    // ---- prologue: reduce 16 rows, wave w owns s=4w..4w+3, 4-way MLP ----
    __shared__ float ssum[16];
    {
        const int wave = threadIdx.x >> 6;
        const int lane = threadIdx.x & 63;
        int rows[4];
        float acc[4];
#pragma unroll
        for (int k = 0; k < 4; ++k) {
            const int s = 4 * wave + k;
            int row;
            if (s < 4)       row = base + s;              // SDD[base+s]
            else if (s < 7)  row = 31 + base + (s - 4);   // SPM
            else if (s < 10) row = 61 + base + (s - 7);   // SFP
            else if (s < 13) row = 91 + base + (s - 10);  // SFM
            else             row = 121 + base + (s - 13); // SFF
            rows[k] = row;
            acc[k] = 0.f;
        }
        for (int r = lane; r < NBX1; r += 64) {
#pragma unroll
            for (int k = 0; k < 4; ++k)
                acc[k] += part[(size_t)rows[k] * PADW + r];   // 4 independent loads
        }
#pragma unroll
        for (int k = 0; k < 4; ++k) {
            float tt = wred_dpp(acc[k]);
            if (lane == 63) ssum[4 * wave + k] = tt;
        }
    }
    __syncthreads();

    // ---- coeff for this chunk's 3 images (threads 0..2) ----
    __shared__ float As[3], Bs[3], Cs[3];
    if (threadIdx.x < 3) {
        const int jl = threadIdx.x;
        const int jj = base + jl;          // coeff index 0..29
        float emin = 1e30f, emax = -1e30f;
        int imax = 0;
        for (int i = 0; i < N_IMG; ++i) {
            float vv = eng[i];
            if (vv < emin) emin = vv;
            if (vv > emax) { emax = vv; imax = i; }   // strict > -> argmax
        }
        const float eref = emin - EPSE;
        float e0 = eng[jj], e1 = eng[jj + 1], e2 = eng[jj + 2];
        float eim = fmaxf(e1, e0);
        float km = KMAXC - DLTKC * (emax - eim) / (emax - eref);
        if (eim < eref) km = KMAXC - DLTKC;
        float eip = fmaxf(e2, e1);
        float kp = KMAXC - DLTKC * (emax - eip) / (emax - eref);
        if (eip < eref) kp = KMAXC - DLTKC;

        float pp = (e2 > e1 && e1 > e0) ? 1.f : 0.f;
        float mm = (e2 < e1 && e1 < e0) ? 1.f : 0.f;
        float nb = 1.f - fmaxf(pp, mm);
        float mp = ((e2 > e1) ? 1.f : 0.f) * nb;
        float mq = ((e2 < e1) ? 1.f : 0.f) * nb;
        float dvmax = fmaxf(fabsf(e2 - e1), fabsf(e0 - e1));
        float dvmin = fminf(fabsf(e2 - e1), fabsf(e0 - e1));
        float a = pp + dvmax * mp + dvmin * mq;   // coeff of tau_p
        float bb = mm + dvmin * mp + dvmax * mq;  // coeff of tau_m
        float Spp = ssum[jl];          // SDD[base+jl]
        float Smm = ssum[jl + 1];      // SDD[base+jl+1]
        float Spm = ssum[4 + jl];
        float Sfp = ssum[7 + jl];
        float Sfm = ssum[10 + jl];
        float Sff = ssum[13 + jl];
        float ntau2 = a * a * Spp + 2.f * a * bb * Spm + bb * bb * Smm;
        float ntau = sqrtf(ntau2);
        float ta = a / ntau, tb = bb / ntau;
        float fpar = ta * Sfp + tb * Sfm;                       // dot(frc, tau)
        float spar = kp * sqrtf(Smm) - km * sqrtf(Spp);         // spr_para magnitude
        float ffpp = Sff - fpar * fpar;                         // |frc_perp|^2
        float strau = ta * (kp * Spm - km * Spp) + tb * (kp * Smm - km * Spm); // dot(spr,tau)
        float Sss = kp * kp * Smm - 2.f * kp * km * Spm + km * km * Spp;       // dot(spr,spr)
        float sspp = Sss - 2.f * spar * strau + spar * spar;    // |spr_perp|^2
        float Ssf = kp * Sfm - km * Sfp;                        // dot(spr,frc)
        float spfp = Ssf - fpar * strau;                        // dot(spr_perp,frc_perp)
        float sw = (2.0f / 3.14159265358979323846f) * atan2f(ffpp, sspp);
        float cc = spfp * sw;
        float g = (jj == imax) ? 2.f : 1.f;                     // .at[i_raw].multiply(2.0)
        float w = (cc - g) * fpar / ntau;
        As[jl] = 1.f - cc;       // A: coeff of frc
        Bs[jl] = kp + w * bb;    // B: coeff of tau_m (=d[j])
        Cs[jl] = w * a - km;     // C: coeff of tau_p (=d[j-1])
    }
    __syncthreads();

    // ---- main body: 8 loads, 3 stores ----
    const int t = blockIdx.x * 256 + threadIdx.x;
    if (t >= NE4) return;
    const float4* pos4 = reinterpret_cast<const float4*>(pos);
    const float4* frc4 = reinterpret_cast<const float4*>(frc);
    float4* out4 = reinterpret_cast<float4*>(out);

    float4 p[5], f[3];
#pragma unroll
    for (int i = 0; i < 5; ++i) p[i] = pos4[(size_t)(j0 - 1 + i) * NE4 + t];
#pragma unroll
    for (int i = 0; i < 3; ++i) f[i] = frc4[(size_t)(j0 + i) * NE4 + t];

    if (c == 0) out4[t] = frc4[t];                                       // out[0]=frc[0]
    if (c == NCH3 - 1) {
        size_t i31 = (size_t)31 * NE4 + t;
        out4[i31] = frc4[i31];                                           // out[31]=frc[31]
    }

    float4 d[4];
#pragma unroll
    for (int i = 0; i < 4; ++i) d[i] = sub4(p[i + 1], p[i]);   // link base+i
#pragma unroll
    for (int jl = 0; jl < 3; ++jl) {
        float ca = As[jl], cb = Bs[jl], cd = Cs[jl];
        float4 o;
        o.x = ca * f[jl].x + cb * d[jl + 1].x + cd * d[jl].x;
        o.y = ca * f[jl].y + cb * d[jl + 1].y + cd * d[jl].y;
        o.z = ca * f[jl].z + cb * d[jl + 1].z + cd * d[jl].z;
        o.w = ca * f[jl].w + cb * d[jl + 1].w + cd * d[jl].w;
        out4[(size_t)(j0 + jl) * NE4 + t] = o;
    }
}

extern "C" void kernel_launch(void* const* d_in, const int* in_sizes, int n_in,
                              void* d_out, int out_size, void* d_ws, size_t ws_size,
                              hipStream_t stream) {
    const float* pos = (const float*)d_in[0];
    const float* frc = (const float*)d_in[1];
    const float* eng = (const float*)d_in[2];
    float* out = (float*)d_out;
    float* ws = (float*)d_ws;
    float* part = ws + OFF_PART;      // NSUM x PADW (slot-major)

    eb_pass1<<<dim3(NBX1, NCH3), 256, 0, stream>>>(pos, frc, part);
    eb_pass2r<<<dim3(NBX2, NCH3), 256, 0, stream>>>(pos, frc, eng, part, out);
}